// Round 1
// baseline (1881.240 us; speedup 1.0000x reference)
//
#include <hip/hip_runtime.h>

// graph_56006373539875: per-edge spring-force scatter
//   v = points[b] - points[a]; v_dir = v/|v|; f_a = -force*v_dir
//   out = external_forces; out[a] += f_a; out[b] -= f_a
//
// Inputs (in_sizes order):
//   d_in[0] points           [100000*3] f32
//   d_in[1] external_forces  [100000*3] f32
//   d_in[2] force            [6400000]  f32
//   d_in[3] edge_a           [6400000]  i32
//   d_in[4] edge_b           [6400000]  i32
// Output: [100000*3] f32

__global__ void edge_scatter_kernel(const float* __restrict__ points,
                                    const float* __restrict__ force,
                                    const int* __restrict__ ea,
                                    const int* __restrict__ eb,
                                    float* __restrict__ out,
                                    int n_edges) {
    int e = blockIdx.x * blockDim.x + threadIdx.x;
    if (e >= n_edges) return;

    int a = ea[e];
    int b = eb[e];

    // 12B gathers; points table (1.2 MB) is L2-resident
    float ax = points[3 * a + 0];
    float ay = points[3 * a + 1];
    float az = points[3 * a + 2];
    float bx = points[3 * b + 0];
    float by = points[3 * b + 1];
    float bz = points[3 * b + 2];

    float vx = bx - ax;
    float vy = by - ay;
    float vz = bz - az;

    float inv = rsqrtf(vx * vx + vy * vy + vz * vz);
    float s = -force[e] * inv;

    float fx = s * vx;
    float fy = s * vy;
    float fz = s * vz;

    atomicAdd(&out[3 * a + 0], fx);
    atomicAdd(&out[3 * a + 1], fy);
    atomicAdd(&out[3 * a + 2], fz);
    atomicAdd(&out[3 * b + 0], -fx);
    atomicAdd(&out[3 * b + 1], -fy);
    atomicAdd(&out[3 * b + 2], -fz);
}

extern "C" void kernel_launch(void* const* d_in, const int* in_sizes, int n_in,
                              void* d_out, int out_size, void* d_ws, size_t ws_size,
                              hipStream_t stream) {
    const float* points = (const float*)d_in[0];
    const float* ext_f  = (const float*)d_in[1];
    const float* force  = (const float*)d_in[2];
    const int*   ea     = (const int*)d_in[3];
    const int*   eb     = (const int*)d_in[4];
    float* out = (float*)d_out;

    const int n_edges = in_sizes[2];

    // out starts as external_forces every launch (d_out is poisoned once
    // before timing and never restored between replays).
    hipMemcpyAsync(d_out, (const void*)ext_f, (size_t)out_size * sizeof(float),
                   hipMemcpyDeviceToDevice, stream);

    const int block = 256;
    const int grid = (n_edges + block - 1) / block;
    edge_scatter_kernel<<<grid, block, 0, stream>>>(points, force, ea, eb, out, n_edges);
}

// Round 2
// 240.455 us; speedup vs baseline: 7.8237x; 7.8237x over previous
//
#include <hip/hip_runtime.h>

// graph_56006373539875: per-edge spring-force scatter, LDS-privatized.
//   v = points[b] - points[a]; v_dir = v/|v|; f_a = -force*v_dir
//   out = external_forces; out[a] += f_a; out[b] -= f_a
//
// R1 showed 38.4M device-scope atomics write-through at 32B each (1.2 GB
// WRITE_SIZE) and cap at ~20 G atomics/s -> 1881 us. This version
// accumulates into per-block LDS tables (node-range privatization) and
// flushes non-atomic partials to d_ws, then reduces.
//
// NR=8 node ranges x 12500 nodes (150 KB LDS/block, 1 block/CU)
// NB=32 edge chunks of 200K edges
// grid = NR*NB = 256 blocks; blockIdx = r*NB + c so blocks sharing chunk c
// are 32 apart -> same XCD under round-robin dispatch (L2 chunk sharing).

#define NR 8
#define NB 32
#define BLOCK 1024

__global__ __launch_bounds__(BLOCK) void edge_scan_kernel(
    const float* __restrict__ points,
    const float* __restrict__ force,
    const int* __restrict__ ea,
    const int* __restrict__ eb,
    float* __restrict__ partial,   // [NB][n_points*3], used when atomic_mode==0
    float* __restrict__ out,       // pre-filled with ext forces when atomic_mode==1
    int n_edges, int n_points, int range, int atomic_mode)
{
    extern __shared__ float lds[];           // range*3 floats
    const int r = blockIdx.x / NB;
    const int c = blockIdx.x % NB;
    const int node0 = r * range;
    const int nwords = range * 3;

    for (int w = threadIdx.x; w < nwords; w += BLOCK) lds[w] = 0.0f;
    __syncthreads();

    const int chunk = (n_edges + NB - 1) / NB;
    const int e0 = c * chunk;
    const int e1 = min(n_edges, e0 + chunk);

    for (int e = e0 + (int)threadIdx.x; e < e1; e += BLOCK) {
        int a = ea[e];
        int b = eb[e];
        int la = a - node0;
        int lb = b - node0;
        bool ha = (unsigned)la < (unsigned)range;
        bool hb = (unsigned)lb < (unsigned)range;
        if (!(ha || hb)) continue;           // skip gathers for non-hits

        float ax = points[3 * a + 0];
        float ay = points[3 * a + 1];
        float az = points[3 * a + 2];
        float bx = points[3 * b + 0];
        float by = points[3 * b + 1];
        float bz = points[3 * b + 2];

        float vx = bx - ax, vy = by - ay, vz = bz - az;
        float s = -force[e] * rsqrtf(vx * vx + vy * vy + vz * vz);
        float fx = s * vx, fy = s * vy, fz = s * vz;   // force_on_a

        if (ha) {
            atomicAdd(&lds[la * 3 + 0], fx);
            atomicAdd(&lds[la * 3 + 1], fy);
            atomicAdd(&lds[la * 3 + 2], fz);
        }
        if (hb) {
            atomicAdd(&lds[lb * 3 + 0], -fx);
            atomicAdd(&lds[lb * 3 + 1], -fy);
            atomicAdd(&lds[lb * 3 + 2], -fz);
        }
    }
    __syncthreads();

    const int base = node0 * 3;              // word offset of this range
    const int total = n_points * 3;
    if (atomic_mode) {
        for (int w = threadIdx.x; w < nwords; w += BLOCK) {
            if (base + w < total) atomicAdd(&out[base + w], lds[w]);
        }
    } else {
        float* dst = partial + (size_t)c * (size_t)total + base;
        for (int w = threadIdx.x; w < nwords; w += BLOCK) {
            if (base + w < total) dst[w] = lds[w];
        }
    }
}

__global__ void reduce_kernel(const float* __restrict__ ext,
                              const float* __restrict__ partial,
                              float* __restrict__ out, int n)
{
    int i = blockIdx.x * blockDim.x + threadIdx.x;
    if (i >= n) return;
    float s = ext[i];
#pragma unroll
    for (int c = 0; c < NB; ++c) s += partial[(size_t)c * (size_t)n + i];
    out[i] = s;
}

extern "C" void kernel_launch(void* const* d_in, const int* in_sizes, int n_in,
                              void* d_out, int out_size, void* d_ws, size_t ws_size,
                              hipStream_t stream) {
    const float* points = (const float*)d_in[0];
    const float* ext_f  = (const float*)d_in[1];
    const float* force  = (const float*)d_in[2];
    const int*   ea     = (const int*)d_in[3];
    const int*   eb     = (const int*)d_in[4];
    float* out = (float*)d_out;
    float* ws  = (float*)d_ws;

    const int n_edges  = in_sizes[2];
    const int total    = out_size;            // n_points*3
    const int n_points = total / 3;
    const int range    = (n_points + NR - 1) / NR;          // 12500
    const size_t lds_bytes = (size_t)range * 3 * sizeof(float);  // 150000
    const size_t need = (size_t)NB * (size_t)total * sizeof(float); // 38.4 MB

    // allow >64KB dynamic LDS (idempotent; not a stream op)
    hipFuncSetAttribute((const void*)edge_scan_kernel,
                        hipFuncAttributeMaxDynamicSharedMemorySize,
                        (int)lds_bytes);

    if (ws_size >= need) {
        edge_scan_kernel<<<NR * NB, BLOCK, lds_bytes, stream>>>(
            points, force, ea, eb, ws, out, n_edges, n_points, range, 0);
        const int rb = 256;
        reduce_kernel<<<(total + rb - 1) / rb, rb, 0, stream>>>(ext_f, ws, out, total);
    } else {
        // fallback: atomic flush directly into out (still 4x fewer atomics)
        hipMemcpyAsync(d_out, (const void*)ext_f, (size_t)total * sizeof(float),
                       hipMemcpyDeviceToDevice, stream);
        edge_scan_kernel<<<NR * NB, BLOCK, lds_bytes, stream>>>(
            points, force, ea, eb, nullptr, out, n_edges, n_points, range, 1);
    }
}